// Round 1
// baseline (3642.457 us; speedup 1.0000x reference)
//
#include <hip/hip_runtime.h>
#include <stdint.h>

#define NBATCH 128
#define NNEUR  4096
#define TLAST  180                      // outputs depend only on steps 0..180
#define DECAY  0.6065306597126334f      // float(exp(-0.5)), rn-rounded from double

// One kernel per time step.
// Grid: 512 blocks = 128 batches x 4 column super-tiles (1024 cols each).
// Block: 256 threads = 4 waves; each wave owns 256 columns (4 consecutive per lane).
// Spikes are stored as raw __ballot words: word w of batch b (w = (c0>>6)+k) holds
// bit u  <->  column c0 + 4*u + k, where c0 = (w>>2)<<8. Decode inverts this.
__global__ __launch_bounds__(256) void lif_step(
    const float* __restrict__ ff, const float* __restrict__ W,
    const float* __restrict__ rec0, float* __restrict__ out,
    float* __restrict__ volts, float* __restrict__ rec,
    float* __restrict__ sum_s, float* __restrict__ sum_v,
    const unsigned long long* __restrict__ bits_old,
    unsigned long long* __restrict__ bits_new, int t)
{
#pragma clang fp contract(off)          // match numpy's separate mul/add roundings
    __shared__ unsigned short slist[NNEUR];
    __shared__ int scnt;

    const int tid  = threadIdx.x;
    const int lane = tid & 63;
    const int wid  = tid >> 6;
    const int bid  = blockIdx.x;
    const int b    = bid >> 2;                         // batch
    const int c0   = ((bid & 3) << 10) + (wid << 8);   // wave's 256-col tile base
    const int n0   = c0 + (lane << 2);                 // this lane's 4 columns

    float4 acc = make_float4(0.f, 0.f, 0.f, 0.f);

    if (t > 0) {
        // ---- decode this batch's spike bitmask into an LDS index list (wave 0) ----
        if (wid == 0) {
            unsigned long long m = bits_old[(b << 6) + lane];   // word `lane`
            int c = __popcll(m);
            int x = c;
            #pragma unroll
            for (int o = 1; o < 64; o <<= 1) {
                int y = __shfl_up(x, (unsigned)o);
                if (lane >= o) x += y;
            }
            if (lane == 63) scnt = x;
            int widx = x - c;                                   // exclusive prefix
            const int jb = ((lane >> 2) << 8) + (lane & 3);     // c0(word) + k
            while (m) {
                int u = __builtin_ctzll(m);
                m &= m - 1;
                slist[widx++] = (unsigned short)(jb + (u << 2));
            }
        }
        __syncthreads();

        // ---- sparse gather: hidden slice = sum of spiking rows of W ----
        const int cnt = scnt;
        const float* wbase = W + n0;
        #pragma unroll 4
        for (int i = 0; i < cnt; ++i) {
            const int j = slist[i];                             // uniform per wave
            const float4 wv = *(const float4*)(wbase + ((size_t)j << 12));
            acc.x += wv.x; acc.y += wv.y; acc.z += wv.z; acc.w += wv.w;
        }
    }

    // ---- elementwise LIF update (exact numpy op order, no contraction) ----
    const size_t idx = ((size_t)b << 12) + (size_t)n0;

    float4 r4 = (t == 0) ? *(const float4*)(rec0 + idx)
                         : *(const float4*)(rec + idx);
    r4.x = r4.x * DECAY + acc.x * 0.5f;
    r4.y = r4.y * DECAY + acc.y * 0.5f;
    r4.z = r4.z * DECAY + acc.z * 0.5f;
    r4.w = r4.w * DECAY + acc.w * 0.5f;

    const float4 f4 = *(const float4*)(ff + (((size_t)b * 200 + (size_t)t) << 12) + n0);

    float4 v4 = make_float4(0.f, 0.f, 0.f, 0.f);
    if (t > 0) v4 = *(const float4*)(volts + idx);
    v4.x = v4.x * DECAY + 0.5f * (f4.x + r4.x);
    v4.y = v4.y * DECAY + 0.5f * (f4.y + r4.y);
    v4.z = v4.z * DECAY + 0.5f * (f4.z + r4.z);
    v4.w = v4.w * DECAY + 0.5f * (f4.w + r4.w);

    const bool s0 = v4.x >= 1.0f, s1 = v4.y >= 1.0f, s2 = v4.z >= 1.0f, s3 = v4.w >= 1.0f;
    if (s0) v4.x = 0.f;
    if (s1) v4.y = 0.f;
    if (s2) v4.z = 0.f;
    if (s3) v4.w = 0.f;

    *(float4*)(volts + idx) = v4;
    *(float4*)(rec + idx)   = r4;

    // ---- new spike bitmask: raw ballots, 4 words per wave ----
    const unsigned long long b0 = __ballot(s0), b1 = __ballot(s1),
                             b2 = __ballot(s2), b3 = __ballot(s3);
    if (lane == 0) {
        unsigned long long* dst = bits_new + (b << 6) + (c0 >> 6);
        dst[0] = b0; dst[1] = b1; dst[2] = b2; dst[3] = b3;
    }

    // ---- recording windows: steps 80..100 -> k0, 101..120 -> k1, ... 161..180 -> k4 ----
    if (t >= 80) {
        const float4 s4 = make_float4(s0 ? 1.f : 0.f, s1 ? 1.f : 0.f,
                                      s2 ? 1.f : 0.f, s3 ? 1.f : 0.f);
        const bool start = (t == 80) || (t == 101) || (t == 121) || (t == 141) || (t == 161);
        float4 ss, sv;
        if (start) {
            ss = s4; sv = v4;
        } else {
            ss = *(const float4*)(sum_s + idx);
            sv = *(const float4*)(sum_v + idx);
            ss.x += s4.x; ss.y += s4.y; ss.z += s4.z; ss.w += s4.w;
            sv.x += v4.x; sv.y += v4.y; sv.z += v4.z; sv.w += v4.w;
        }
        *(float4*)(sum_s + idx) = ss;
        *(float4*)(sum_v + idx) = sv;

        if (t >= 100 && ((t - 100) % 20) == 0) {
            const int k = (t - 100) / 20;
            const size_t oidx = (((size_t)b * 5 + (size_t)k) << 12) + n0;
            float* rates = out;
            float* vavg  = out + (size_t)NBATCH * 5 * NNEUR;
            float* srec  = out + (size_t)NBATCH * 5 * NNEUR * 2;
            *(float4*)(rates + oidx) = make_float4(ss.x / 20.f, ss.y / 20.f,
                                                   ss.z / 20.f, ss.w / 20.f);
            *(float4*)(vavg + oidx)  = make_float4(sv.x / 20.f, sv.y / 20.f,
                                                   sv.z / 20.f, sv.w / 20.f);
            *(float4*)(srec + oidx)  = s4;
        }
    }
}

extern "C" void kernel_launch(void* const* d_in, const int* in_sizes, int n_in,
                              void* d_out, int out_size, void* d_ws, size_t ws_size,
                              hipStream_t stream) {
    const float* ff   = (const float*)d_in[0];   // [128][200][4096] f32
    const float* W    = (const float*)d_in[1];   // [4096][4096] f32 (Wab_T)
    const float* rec0 = (const float*)d_in[2];   // [128][4096] f32
    float* out = (float*)d_out;                  // rates | volts_avg | spikes_rec

    char* ws = (char*)d_ws;
    const size_t STATE = (size_t)NBATCH * NNEUR * sizeof(float);   // 2 MB
    float* volts = (float*)(ws);
    float* rec   = (float*)(ws + STATE);
    float* sum_s = (float*)(ws + 2 * STATE);
    float* sum_v = (float*)(ws + 3 * STATE);
    unsigned long long* bits = (unsigned long long*)(ws + 4 * STATE);
    const int BWORDS = NBATCH * (NNEUR / 64);    // 8192 words per buffer

    for (int t = 0; t <= TLAST; ++t) {
        lif_step<<<dim3(512), dim3(256), 0, stream>>>(
            ff, W, rec0, out, volts, rec, sum_s, sum_v,
            bits + (size_t)(t & 1) * BWORDS,
            bits + (size_t)((t + 1) & 1) * BWORDS, t);
    }
}